// Round 1
// baseline (96.005 us; speedup 1.0000x reference)
//
#include <hip/hip_runtime.h>
#include <math.h>

// Tropical (max-plus) matmul: out[b,o] = max_k ( x[b,k] + W[o,k] )
// x: (2048, 512) f32 row-major, W: (512, 512) f32 row-major, out: (2048, 512) f32.
// Pure VALU-bound (no MFMA for max-plus). GEMM-style tiling:
//   64x64 output tile / block (256 thr), BK=32, 4x4 register tile per thread.
//   LDS tiles k-major with +4 pad: conflict-free ds_read_b128, 16B-aligned rows.
//   k unrolled by 2 so the reduce is fmaxf(acc, fmaxf(s0,s1)) -> v_max3_f32.
//   Register prefetch pipeline hides global latency (grid = 256 blocks = 1/CU).

#define B_ROWS 2048
#define K_DIM  512
#define O_DIM  512
#define BM 64
#define BN 64
#define BK 32
#define PAD 4   // row stride 68 floats = 272B: 16B-aligned, breaks write-bank aliasing

__global__ __launch_bounds__(256) void tropical_kernel(
    const float* __restrict__ x, const float* __restrict__ W,
    float* __restrict__ out)
{
    __shared__ float xs[BK][BM + PAD];
    __shared__ float ws[BK][BN + PAD];

    const int t  = threadIdx.x;
    const int tx = t & 15;          // 0..15 -> N direction
    const int ty = t >> 4;          // 0..15 -> M direction
    const int tm = ty * 4;
    const int tn = tx * 4;
    const int bm = blockIdx.y * BM;
    const int bn = blockIdx.x * BN;

    // Staging assignment: thread t loads float4 at (row0, kv0) and (row0+32, kv0)
    // from both x and W. Coalesced along k (contiguous in both inputs).
    const int row0 = t >> 3;         // 0..31
    const int kv0  = (t & 7) * 4;    // 0,4,...,28

    float acc[4][4];
#pragma unroll
    for (int i = 0; i < 4; ++i)
#pragma unroll
        for (int j = 0; j < 4; ++j) acc[i][j] = -INFINITY;

    float4 fx0, fx1, fw0, fw1;
    // prologue: fetch tile 0 into registers
    {
        const float* xp = x + (bm + row0) * K_DIM + kv0;
        fx0 = *(const float4*)xp;
        fx1 = *(const float4*)(xp + 32 * K_DIM);
        const float* wp = W + (bn + row0) * K_DIM + kv0;
        fw0 = *(const float4*)wp;
        fw1 = *(const float4*)(wp + 32 * K_DIM);
    }

    const int NT = K_DIM / BK;  // 16
    for (int kt = 0; kt < NT; ++kt) {
        // drain staged registers into LDS (transposed, k-major)
        const float* f;
        f = (const float*)&fx0;
#pragma unroll
        for (int j = 0; j < 4; ++j) xs[kv0 + j][row0] = f[j];
        f = (const float*)&fx1;
#pragma unroll
        for (int j = 0; j < 4; ++j) xs[kv0 + j][row0 + 32] = f[j];
        f = (const float*)&fw0;
#pragma unroll
        for (int j = 0; j < 4; ++j) ws[kv0 + j][row0] = f[j];
        f = (const float*)&fw1;
#pragma unroll
        for (int j = 0; j < 4; ++j) ws[kv0 + j][row0 + 32] = f[j];
        __syncthreads();

        // prefetch next tile into registers (hidden under compute below)
        if (kt + 1 < NT) {
            const int k0 = (kt + 1) * BK;
            const float* xp = x + (bm + row0) * K_DIM + k0 + kv0;
            fx0 = *(const float4*)xp;
            fx1 = *(const float4*)(xp + 32 * K_DIM);
            const float* wp = W + (bn + row0) * K_DIM + k0 + kv0;
            fw0 = *(const float4*)wp;
            fw1 = *(const float4*)(wp + 32 * K_DIM);
        }

        // compute: 32 k-steps, paired for v_max3_f32 formation
#pragma unroll
        for (int k = 0; k < BK; k += 2) {
            float4 a0 = *(const float4*)&xs[k][tm];
            float4 a1 = *(const float4*)&xs[k + 1][tm];
            float4 b0 = *(const float4*)&ws[k][tn];
            float4 b1 = *(const float4*)&ws[k + 1][tn];
            const float* A0 = (const float*)&a0;
            const float* A1 = (const float*)&a1;
            const float* B0 = (const float*)&b0;
            const float* B1 = (const float*)&b1;
#pragma unroll
            for (int i = 0; i < 4; ++i) {
#pragma unroll
                for (int j = 0; j < 4; ++j) {
                    float s0 = A0[i] + B0[j];
                    float s1 = A1[i] + B1[j];
                    acc[i][j] = fmaxf(acc[i][j], fmaxf(s0, s1));
                }
            }
        }
        __syncthreads();
    }

    // epilogue: coalesced float4 stores
#pragma unroll
    for (int i = 0; i < 4; ++i) {
        float4 v;
        v.x = acc[i][0]; v.y = acc[i][1]; v.z = acc[i][2]; v.w = acc[i][3];
        *(float4*)(out + (size_t)(bm + tm + i) * O_DIM + bn + tn) = v;
    }
}

extern "C" void kernel_launch(void* const* d_in, const int* in_sizes, int n_in,
                              void* d_out, int out_size, void* d_ws, size_t ws_size,
                              hipStream_t stream) {
    const float* x = (const float*)d_in[0];   // (2048, 512)
    const float* W = (const float*)d_in[1];   // (512, 512)
    float* out = (float*)d_out;               // (2048, 512)

    dim3 grid(O_DIM / BN, B_ROWS / BM);       // (8, 32) = 256 blocks
    tropical_kernel<<<grid, 256, 0, stream>>>(x, W, out);
}